// Round 4
// baseline (336.154 us; speedup 1.0000x reference)
//
#include <hip/hip_runtime.h>
#include <math.h>

typedef __attribute__((ext_vector_type(8))) short short8;
typedef __attribute__((ext_vector_type(4))) short short4v;
typedef __attribute__((ext_vector_type(4))) float f32x4;

#define D 160
#define NTOK (256*512)   // 131072 rows
#define MT 64            // rows per workgroup
#define BLK 128          // 2 waves; each wave owns 32 rows (2 x 16-row groups)

__device__ __forceinline__ short f2bf(float f) {
  union { float f; unsigned u; } v; v.f = f;
  return (short)((v.u + 0x8000u) >> 16);   // round-half-up
}
__device__ __forceinline__ float bf2f(short s) {
  union { float f; unsigned u; } v;
  v.u = ((unsigned)(unsigned short)s) << 16;
  return v.f;
}

// LDS tile: 64 rows x 320 bf16, stride 320 (40960 B -> 4 blocks/CU).
// XOR-swizzle 16B granules (low 3 bits) so 16 rows at fixed col spread
// across all 32 banks (2 lanes/bank = free).
__device__ __forceinline__ int lds_idx(int row, int col) {
  return row * 320 + ((((col >> 3) ^ (row & 7)) << 3) | (col & 7));
}

// Pack weights to bf16 in MFMA B-FRAGMENT ORDER:
//   frag f = ks*10 + nt;  element (f, lane, j) = W[n][k],
//   n = nt*16 + (lane&15), k = ks*32 + (lane>>4)*8 + j.
__global__ __launch_bounds__(256) void prep_kernel(
    const float* __restrict__ W2, const float* __restrict__ W3,
    const float* __restrict__ W1, const float* __restrict__ W4,
    const float* __restrict__ W5, short* __restrict__ ws) {
  int i = blockIdx.x * 256 + threadIdx.x;
  if (i >= 128000) return;
  if (i < 51200) {
    int f = i >> 9, r = i & 511;
    int lane = r >> 3, j = r & 7;
    int ks = f / 10, nt = f % 10;
    int n = nt * 16 + (lane & 15);
    int k = ks * 32 + (lane >> 4) * 8 + j;
    float v = (k < 160) ? W2[n * 160 + k] : W3[n * 160 + (k - 160)];
    ws[i] = f2bf(v);
  } else {
    int idx = i - 51200;
    int which = idx / 25600;      // 0=W1, 1=W4, 2=W5
    int e = idx % 25600;
    int f = e >> 9, r = e & 511;
    int lane = r >> 3, j = r & 7;
    int ks = f / 10, nt = f % 10;
    int n = nt * 16 + (lane & 15);
    int k = ks * 32 + (lane >> 4) * 8 + j;
    const float* W = (which == 0) ? W1 : (which == 1) ? W4 : W5;
    ws[i] = f2bf(W[n * 160 + k]);
  }
}

// Fused GRN, 2 waves x 32 rows. LDS lifetime per wave-local 32-row slab:
//   cols 0:160   = x (bf16), live until residual in phase 3
//   cols 160:320 = c -> eta2 (phase1) -> eta1 (phase2); within-wave DS
//                  program order makes read-then-overwrite safe.
__global__ __launch_bounds__(BLK, 2) void grn_main(
    const float* __restrict__ x, const float* __restrict__ c,
    const short* __restrict__ wcatf, const short* __restrict__ w1f,
    const short* __restrict__ w4f, const short* __restrict__ w5f,
    const float* __restrict__ b2, const float* __restrict__ b1,
    const float* __restrict__ b4, const float* __restrict__ b5,
    const float* __restrict__ gamma, const float* __restrict__ beta,
    float* __restrict__ out) {
  __shared__ __align__(16) short Acat[MT * 320];   // 40960 B

  const int tid  = threadIdx.x;
  const int lane = tid & 63;
  const int wave = tid >> 6;      // 0..1
  const int lr   = lane & 15;
  const int quad = lane >> 4;
  const int rowbase = blockIdx.x * MT;
  const int m0 = wave * 32;

  // ---------------- phase 0: stage x,c -> bf16 LDS ---------------------------
  {
    const f32x4* xg = (const f32x4*)(x + (size_t)rowbase * D);
    const f32x4* cg = (const f32x4*)(c + (size_t)rowbase * D);
#pragma unroll
    for (int i = 0; i < 20; ++i) {
      int g = tid + BLK * i;          // float4 index in 64x40 tile
      int row = g / 40, col4 = g - row * 40;
      f32x4 vx = xg[g];
      f32x4 vc = cg[g];
      short4v sx, sc;
#pragma unroll
      for (int j = 0; j < 4; ++j) { sx[j] = f2bf(vx[j]); sc[j] = f2bf(vc[j]); }
      *(short4v*)&Acat[lds_idx(row, col4 * 4)]       = sx;
      *(short4v*)&Acat[lds_idx(row, 160 + col4 * 4)] = sc;
    }
  }
  __syncthreads();   // the only barrier

  // ---------------- phase 1: eta2 = ELU([x|c] @ wcat^T + b2) -> cols 160: ----
  {
    f32x4 acc[2][10];
#pragma unroll
    for (int h = 0; h < 2; ++h)
#pragma unroll
      for (int nt = 0; nt < 10; ++nt) acc[h][nt] = (f32x4){0.f, 0.f, 0.f, 0.f};
    const short* wp = wcatf + lane * 8;
#pragma unroll
    for (int ks = 0; ks < 10; ++ks) {
      short8 af0 = *(const short8*)&Acat[lds_idx(m0 + lr,      ks * 32 + quad * 8)];
      short8 af1 = *(const short8*)&Acat[lds_idx(m0 + 16 + lr, ks * 32 + quad * 8)];
#pragma unroll
      for (int nt = 0; nt < 10; ++nt) {
        short8 bf = *(const short8*)(wp + ((ks * 10 + nt) << 9));
        acc[0][nt] = __builtin_amdgcn_mfma_f32_16x16x32_bf16(af0, bf, acc[0][nt], 0, 0, 0);
        acc[1][nt] = __builtin_amdgcn_mfma_f32_16x16x32_bf16(af1, bf, acc[1][nt], 0, 0, 0);
      }
    }
#pragma unroll
    for (int nt = 0; nt < 10; ++nt) {
      float bias = b2[nt * 16 + lr];
#pragma unroll
      for (int h = 0; h < 2; ++h)
#pragma unroll
        for (int r = 0; r < 4; ++r) {
          float v = acc[h][nt][r] + bias;
          v = v > 0.f ? v : (__expf(v) - 1.f);   // ELU
          Acat[lds_idx(m0 + h * 16 + quad * 4 + r, 160 + nt * 16 + lr)] = f2bf(v);
        }
    }
  }

  // ---------------- phase 2: eta1 = eta2 @ W1^T + b1 (in place) --------------
  {
    f32x4 acc[2][10];
#pragma unroll
    for (int h = 0; h < 2; ++h)
#pragma unroll
      for (int nt = 0; nt < 10; ++nt) acc[h][nt] = (f32x4){0.f, 0.f, 0.f, 0.f};
    const short* wp = w1f + lane * 8;
#pragma unroll
    for (int ks = 0; ks < 5; ++ks) {
      short8 af0 = *(const short8*)&Acat[lds_idx(m0 + lr,      160 + ks * 32 + quad * 8)];
      short8 af1 = *(const short8*)&Acat[lds_idx(m0 + 16 + lr, 160 + ks * 32 + quad * 8)];
#pragma unroll
      for (int nt = 0; nt < 10; ++nt) {
        short8 bf = *(const short8*)(wp + ((ks * 10 + nt) << 9));
        acc[0][nt] = __builtin_amdgcn_mfma_f32_16x16x32_bf16(af0, bf, acc[0][nt], 0, 0, 0);
        acc[1][nt] = __builtin_amdgcn_mfma_f32_16x16x32_bf16(af1, bf, acc[1][nt], 0, 0, 0);
      }
    }
#pragma unroll
    for (int nt = 0; nt < 10; ++nt) {
      float bias = b1[nt * 16 + lr];
#pragma unroll
      for (int h = 0; h < 2; ++h)
#pragma unroll
        for (int r = 0; r < 4; ++r) {
          float v = acc[h][nt][r] + bias;
          Acat[lds_idx(m0 + h * 16 + quad * 4 + r, 160 + nt * 16 + lr)] = f2bf(v);
        }
    }
  }

  // ---------------- phase 3: GLU + residual + LayerNorm -----------------------
  {
    // pass V: v = eta1 @ W5^T + b5, packed to bf16 pairs (40 VGPRs)
    int vpack[2][10][2];
    {
      f32x4 accv[2][10];
#pragma unroll
      for (int h = 0; h < 2; ++h)
#pragma unroll
        for (int nt = 0; nt < 10; ++nt) accv[h][nt] = (f32x4){0.f, 0.f, 0.f, 0.f};
      const short* wp5 = w5f + lane * 8;
#pragma unroll
      for (int ks = 0; ks < 5; ++ks) {
        short8 af0 = *(const short8*)&Acat[lds_idx(m0 + lr,      160 + ks * 32 + quad * 8)];
        short8 af1 = *(const short8*)&Acat[lds_idx(m0 + 16 + lr, 160 + ks * 32 + quad * 8)];
#pragma unroll
        for (int nt = 0; nt < 10; ++nt) {
          short8 bv = *(const short8*)(wp5 + ((ks * 10 + nt) << 9));
          accv[0][nt] = __builtin_amdgcn_mfma_f32_16x16x32_bf16(af0, bv, accv[0][nt], 0, 0, 0);
          accv[1][nt] = __builtin_amdgcn_mfma_f32_16x16x32_bf16(af1, bv, accv[1][nt], 0, 0, 0);
        }
      }
#pragma unroll
      for (int nt = 0; nt < 10; ++nt) {
        float bvs = b5[nt * 16 + lr];
#pragma unroll
        for (int h = 0; h < 2; ++h) {
          unsigned p0 = (unsigned short)f2bf(accv[h][nt][0] + bvs)
                      | ((unsigned)(unsigned short)f2bf(accv[h][nt][1] + bvs) << 16);
          unsigned p1 = (unsigned short)f2bf(accv[h][nt][2] + bvs)
                      | ((unsigned)(unsigned short)f2bf(accv[h][nt][3] + bvs) << 16);
          vpack[h][nt][0] = (int)p0;
          vpack[h][nt][1] = (int)p1;
        }
      }
    }

    // pass G: g = eta1 @ W4^T + b4
    f32x4 accg[2][10];
#pragma unroll
    for (int h = 0; h < 2; ++h)
#pragma unroll
      for (int nt = 0; nt < 10; ++nt) accg[h][nt] = (f32x4){0.f, 0.f, 0.f, 0.f};
    {
      const short* wp4 = w4f + lane * 8;
#pragma unroll
      for (int ks = 0; ks < 5; ++ks) {
        short8 af0 = *(const short8*)&Acat[lds_idx(m0 + lr,      160 + ks * 32 + quad * 8)];
        short8 af1 = *(const short8*)&Acat[lds_idx(m0 + 16 + lr, 160 + ks * 32 + quad * 8)];
#pragma unroll
        for (int nt = 0; nt < 10; ++nt) {
          short8 bg = *(const short8*)(wp4 + ((ks * 10 + nt) << 9));
          accg[0][nt] = __builtin_amdgcn_mfma_f32_16x16x32_bf16(af0, bg, accg[0][nt], 0, 0, 0);
          accg[1][nt] = __builtin_amdgcn_mfma_f32_16x16x32_bf16(af1, bg, accg[1][nt], 0, 0, 0);
        }
      }
    }

    // glu + residual (x from LDS) + LN stats
    float y[2][10][4];
    float sum[2][4], ssq[2][4];
#pragma unroll
    for (int h = 0; h < 2; ++h)
#pragma unroll
      for (int r = 0; r < 4; ++r) { sum[h][r] = 0.f; ssq[h][r] = 0.f; }
#pragma unroll
    for (int nt = 0; nt < 10; ++nt) {
      float bgs = b4[nt * 16 + lr];
#pragma unroll
      for (int h = 0; h < 2; ++h) {
#pragma unroll
        for (int r = 0; r < 4; ++r) {
          float g = accg[h][nt][r] + bgs;
          int p = vpack[h][nt][r >> 1];
          float v = bf2f((short)((r & 1) ? (p >> 16) : (p & 0xffff)));
          float glu = v * __builtin_amdgcn_rcpf(1.f + __expf(-g));
          float xv = bf2f(Acat[lds_idx(m0 + h * 16 + quad * 4 + r, nt * 16 + lr)]);
          float yy = xv + glu;
          y[h][nt][r] = yy;
          sum[h][r] += yy;
          ssq[h][r] += yy * yy;
        }
      }
    }
    // reduce across 16 lanes of the quad-group
#pragma unroll
    for (int off = 1; off < 16; off <<= 1) {
#pragma unroll
      for (int h = 0; h < 2; ++h)
#pragma unroll
        for (int r = 0; r < 4; ++r) {
          sum[h][r] += __shfl_xor(sum[h][r], off, 64);
          ssq[h][r] += __shfl_xor(ssq[h][r], off, 64);
        }
    }
    float mean[2][4], rstd[2][4];
#pragma unroll
    for (int h = 0; h < 2; ++h)
#pragma unroll
      for (int r = 0; r < 4; ++r) {
        mean[h][r] = sum[h][r] * (1.f / 160.f);
        float var = ssq[h][r] * (1.f / 160.f) - mean[h][r] * mean[h][r];
        rstd[h][r] = __builtin_amdgcn_rsqf(var + 1e-5f);
      }
#pragma unroll
    for (int nt = 0; nt < 10; ++nt) {
      int col = nt * 16 + lr;
      float ga = gamma[col];
      float be = beta[col];
#pragma unroll
      for (int h = 0; h < 2; ++h)
#pragma unroll
        for (int r = 0; r < 4; ++r) {
          int row = rowbase + m0 + h * 16 + quad * 4 + r;
          out[(size_t)row * D + col] = (y[h][nt][r] - mean[h][r]) * rstd[h][r] * ga + be;
        }
    }
  }
}

extern "C" void kernel_launch(void* const* d_in, const int* in_sizes, int n_in,
                              void* d_out, int out_size, void* d_ws, size_t ws_size,
                              hipStream_t stream) {
  const float* x     = (const float*)d_in[0];
  const float* c     = (const float*)d_in[1];
  const float* W2    = (const float*)d_in[2];
  const float* b2    = (const float*)d_in[3];
  const float* W3    = (const float*)d_in[4];
  const float* W1    = (const float*)d_in[5];
  const float* b1    = (const float*)d_in[6];
  const float* W4    = (const float*)d_in[7];
  const float* b4    = (const float*)d_in[8];
  const float* W5    = (const float*)d_in[9];
  const float* b5    = (const float*)d_in[10];
  const float* gamma = (const float*)d_in[11];
  const float* beta  = (const float*)d_in[12];

  short* ws = (short*)d_ws;   // 256000 B; re-packed every launch
  prep_kernel<<<500, 256, 0, stream>>>(W2, W3, W1, W4, W5, ws);

  const short* wcatf = ws;
  const short* w1f   = ws + 51200;
  const short* w4f   = w1f + 25600;
  const short* w5f   = w4f + 25600;

  grn_main<<<NTOK / MT, BLK, 0, stream>>>(x, c, wcatf, w1f, w4f, w5f,
                                          b2, b1, b4, b5, gamma, beta,
                                          (float*)d_out);
}